// Round 11
// baseline (2276.448 us; speedup 1.0000x reference)
//
#include <hip/hip_runtime.h>
#include <hip/hip_bf16.h>
#include <math.h>

#define BB 8
#define TT 4096
#define HHD 128
#define NBK 6
#define KNN 20
#define BT (BB*TT)

typedef __attribute__((ext_vector_type(8))) short bf16x8;
typedef __attribute__((ext_vector_type(4))) float f32x4;

__device__ __forceinline__ float b2f(unsigned short u){
  return __uint_as_float(((unsigned int)u) << 16);
}
__device__ __forceinline__ unsigned short f2b(float f){
  unsigned int x = __float_as_uint(f);
  unsigned int r = (x + 0x7fffu + ((x >> 16) & 1u)) >> 16;   // RTNE
  return (unsigned short)r;
}
// dtype-agnostic parameter load: f32m=1 -> buffer is float32, else bf16
__device__ __forceinline__ float ldp(const void* base, int i, int f32m){
  return f32m ? ((const float*)base)[i] : b2f(((const unsigned short*)base)[i]);
}
__device__ __forceinline__ float lo2f(unsigned int u){ return __uint_as_float(u << 16); }
__device__ __forceinline__ float hi2f(unsigned int u){ return __uint_as_float(u & 0xffff0000u); }
__device__ __forceinline__ unsigned int relu2(unsigned int u){
  unsigned int s = u & 0x80008000u;
  unsigned int m = s | (s - (s >> 15));
  return u & ~m;
}
__device__ __forceinline__ bf16x8 relu8(bf16x8 x){
  union { bf16x8 v; unsigned int u[4]; } t; t.v = x;
  t.u[0] = relu2(t.u[0]); t.u[1] = relu2(t.u[1]);
  t.u[2] = relu2(t.u[2]); t.u[3] = relu2(t.u[3]);
  return t.v;
}
// two-term bf16 split of fp32 v, packed (hi | lo<<16). v = hi + lo + res,
// |res| <= 2^-17 |v| (Sterbenz: v - b2f(hi) exact, then RTNE to bf16).
__device__ __forceinline__ unsigned int splitpk(float v){
  unsigned short h = f2b(v);
  float hv = b2f(h);
  unsigned short l = f2b(v - hv);
  return (unsigned int)h | ((unsigned int)l << 16);
}

// ---------------- dtype detector (64-lane parallel) + barrier-counter zeroing ----------------
__global__ void k_detect(const unsigned short* __restrict__ wpos_raw, int* __restrict__ flag,
                         unsigned int* __restrict__ bar){
  int lane = threadIdx.x;   // 64 threads
  if (lane < 8) bar[lane] = 0u;    // re-zeroed every graph replay, before k_block6 (stream-ordered)
  int cnt = 0;
  for (int i = lane; i < 384; i += 64) {
    unsigned int e = (wpos_raw[i] >> 7) & 0xFFu;
    if (e >= 0x90u) cnt++;
  }
  #pragma unroll
  for (int off = 32; off > 0; off >>= 1) cnt += __shfl_down(cnt, off);
  if (lane == 0) *flag = (cnt > 10) ? 1 : 0;
}

// ---------------- prep: p -> float4 (x,y,z,|p|^2) ----------------
__global__ __launch_bounds__(256) void k_prep_points(const void* __restrict__ p,
                                                     const int* __restrict__ flagp,
                                                     float4* __restrict__ pf4){
  int r = blockIdx.x*256 + threadIdx.x;
  if (r >= BT) return;
  int f32m = *flagp;
  float x = ldp(p, r*3+0, f32m), y = ldp(p, r*3+1, f32m), z = ldp(p, r*3+2, f32m);
  float sq = __fadd_rn(__fadd_rn(__fmul_rn(x,x), __fmul_rn(y,y)), __fmul_rn(z,z));
  pf4[r] = make_float4(x, y, z, sq);
}

// ---------------- net0 = p @ W_pos + b_pos  (bf16 out) ----------------
__global__ __launch_bounds__(256) void k_net0(const float4* __restrict__ pf4,
                                              const void* __restrict__ Wpos,
                                              const void* __restrict__ bpos,
                                              const int* __restrict__ flagp,
                                              unsigned short* __restrict__ netA){
  int t = blockIdx.x*256 + threadIdx.x;   // over BT*128
  int f32m = *flagp;
  int c = t & 127, r = t >> 7;
  float4 q = pf4[r];
  float v = ldp(bpos, c, f32m);
  v = fmaf(q.x, ldp(Wpos, c,       f32m), v);
  v = fmaf(q.y, ldp(Wpos, 128 + c, f32m), v);
  v = fmaf(q.z, ldp(Wpos, 256 + c, f32m), v);
  netA[t] = f2b(v);
}

// ---------------- transpose all weights to [N][K] bf16 ----------------
// layout in wT (shorts): W0T 6*32768 | W1T 6*16384 | WsT 6*32768 | WoT 6*16384 | WcT 16384
__global__ __launch_bounds__(256) void k_transpose(const void* __restrict__ W0,
                                                   const void* __restrict__ W1,
                                                   const void* __restrict__ Ws,
                                                   const void* __restrict__ Wo,
                                                   const void* __restrict__ Wc,
                                                   const int* __restrict__ flagp,
                                                   unsigned short* __restrict__ wT){
  int t = blockIdx.x*256 + threadIdx.x;
  int f32m = *flagp;
  if (t < 196608) {                    // W0T: per block [128][256]
    int i = t >> 15; int rem = t & 32767; int n = rem >> 8; int k = rem & 255;
    wT[t] = f2b(ldp(W0, i*32768 + k*128 + n, f32m));
  } else if (t < 294912) {             // W1T: [128][128]
    int u = t - 196608; int i = u >> 14; int rem = u & 16383; int n = rem >> 7; int k = rem & 127;
    wT[t] = f2b(ldp(W1, i*16384 + k*128 + n, f32m));
  } else if (t < 491520) {             // WsT: [128][256]
    int u = t - 294912; int i = u >> 15; int rem = u & 32767; int n = rem >> 8; int k = rem & 255;
    wT[t] = f2b(ldp(Ws, i*32768 + k*128 + n, f32m));
  } else if (t < 589824) {             // WoT: [128][128]
    int u = t - 491520; int i = u >> 14; int rem = u & 16383; int n = rem >> 7; int k = rem & 127;
    wT[t] = f2b(ldp(Wo, i*16384 + k*128 + n, f32m));
  } else if (t < 606208) {             // WcT: [128][128]
    int u = t - 589824; int n = u >> 7; int k = u & 127;
    wT[t] = f2b(ldp(Wc, k*128 + n, f32m));
  }
}

// sorted ascending insert into (ld,li)[20], strict '<' keeps earliest index on ties
#define INS(act, dv, iv) do { bool A_ = (act); float D_ = (dv); int I_ = (iv);        \
  _Pragma("unroll")                                                                    \
  for (int j = 19; j >= 1; --j) {                                                      \
    bool cj = A_ && (D_ < ld[j]); bool cm = A_ && (D_ < ld[j-1]);                      \
    ld[j] = cj ? (cm ? ld[j-1] : D_) : ld[j];                                          \
    li[j] = cj ? (cm ? li[j-1] : I_) : li[j];                                          \
  }                                                                                    \
  { bool c0 = A_ && (D_ < ld[0]); ld[0] = c0 ? D_ : ld[0]; li[0] = c0 ? I_ : li[0]; } \
} while(0)

#define KCAP   20       // admission stack depth (float2, slot-major)
#define MARGIN 0.02f    // > worst-case MFMA-d2 error (~5e-3); filter-only, exact recompute follows

// batched exact-recompute + sorted-insert flush. All stacked entries are from
// the CURRENT chunk (we flush at every chunk end), so exact d2 is recomputed
// from the live float4 tile with the bit-identical R2 formula.
#define KNN_FLUSH() do {                                                               \
  int mc_ = cnt;                                                                       \
  _Pragma("unroll")                                                                    \
  for (int o_ = 32; o_ > 0; o_ >>= 1) { int t_ = __shfl_xor(mc_, o_); mc_ = mc_ > t_ ? mc_ : t_; } \
  _Pragma("unroll 1")                                                                  \
  for (int u_ = 0; u_ < mc_; ++u_) {                                                   \
    float2 e_ = stk[u_*256 + tid];                                                     \
    bool act_ = u_ < cnt;                                                              \
    int piv_ = __float_as_int(e_.y);                                                   \
    float4 pp_ = tilef4[act_ ? (piv_ - ch*512) : 0];                                   \
    float dot_ = __fadd_rn(__fadd_rn(__fmul_rn(q.x,pp_.x), __fmul_rn(q.y,pp_.y)),      \
                           __fmul_rn(q.z,pp_.z));                                      \
    float d2e_ = __fsub_rn(__fadd_rn(q.w, pp_.w), __fmul_rn(2.0f, dot_));              \
    INS(act_, d2e_, piv_);                                                             \
  }                                                                                    \
  cnt = 0;                                                                             \
  atomicMin(&sthr[qlocal], __float_as_uint(fmaxf(ld[19], 0.0f)));                      \
  threshP = fminf(ld[19], __uint_as_float(sthr[qlocal])) + MARGIN;                     \
} while(0)

// ---------------- KNN: MFMA-filtered scan, 4 waves / 64 queries ----------------
// Proven 174us version (R6/R9). Untouched.
__global__ __launch_bounds__(256) void k_knn(const float4* __restrict__ pf4,
                                             const void* __restrict__ Wc,
                                             const void* __restrict__ bc,
                                             const int* __restrict__ flagp,
                                             unsigned short* __restrict__ idx16,
                                             unsigned short* __restrict__ wsoftb){
  // scan:  tilef4 [0,8192) | tilesp [8192,16384) | stk [16384,57344)
  // merge: lsd [16384,36864) | lsi [36864,57344)   (overlay, stacks dead)
  __shared__ __align__(16) char smem[57344];
  __shared__ unsigned int sthr[64];              // per-query shared threshold (float bits)
  float4* tilef4 = (float4*)smem;                // [512] original coords (exact recompute)
  uint4*  tilesp = (uint4*)(smem + 8192);        // [512] packed hi/lo splits (MFMA A source)
  float2* stk    = (float2*)(smem + 16384);      // [KCAP][256] (d2approx, idx-bits)
  float*  lsd    = (float*)(smem + 16384);       // [256][20] (merge phase)
  int*    lsi    = (int*)(smem + 36864);         // [256][20] (merge phase)

  int tid  = threadIdx.x;
  int wv   = tid >> 6, lane = tid & 63;
  int cq   = lane & 15;          // query column within wave
  int kg   = lane >> 4;          // k-group for A/B supply; merge partition for D rows
  int qlocal = wv*16 + cq;       // block-local query 0..63
  int b    = blockIdx.x >> 6;    // batch (64 blocks of 64 queries per batch)
  int f32m = *flagp;
  float4 q = pf4[blockIdx.x*64 + qlocal];

  if (tid < 64) sthr[tid] = 0x7F7FFFFFu;         // +3.4e38

  // B fragment (queries) built once: lane supplies query cq, k-slots kg*8..+8
  union FRU { bf16x8 v; unsigned int u[4]; };
  FRU bfr;
  {
    float e = (kg == 0) ? -2.0f*q.x : -2.0f*q.z;
    unsigned int ehl = splitpk(e);
    unsigned int eh = ehl & 0xffffu, el = ehl >> 16;
    float f = (kg == 0) ? -2.0f*q.y : q.w;
    unsigned int fhl = splitpk(f);
    unsigned int fh = fhl & 0xffffu, fl = fhl >> 16;
    unsigned int v0 = eh | (eh << 16);
    unsigned int v1 = el | (el << 16);
    unsigned int v2 = (kg == 0) ? (fh | (fh << 16)) : 0x3F803F80u;
    unsigned int v3 = (kg == 0) ? (fl | (fl << 16)) : fhl;
    if (kg >= 2) { v0 = 0; v1 = 0; v2 = 0; v3 = 0; }
    bfr.u[0] = v0; bfr.u[1] = v1; bfr.u[2] = v2; bfr.u[3] = v3;
  }
  const f32x4 zf = {0.f, 0.f, 0.f, 0.f};

  float ld[20]; int li[20];
  #pragma unroll
  for (int j = 0; j < 20; ++j) { ld[j] = 3.0e38f; li[j] = 0; }
  float threshP = 3.0e38f;
  int cnt = 0;

  for (int ch = 0; ch < 8; ++ch) {
    __syncthreads();
    {   // stage 512 points: float4 tile + split tile
      const float4* src = pf4 + (b << 12) + ch*512;
      float4 a0 = src[tid], a1 = src[tid + 256];
      tilef4[tid]       = a0;
      tilef4[tid + 256] = a1;
      tilesp[tid]       = make_uint4(splitpk(a0.x), splitpk(a0.y), splitpk(a0.z), splitpk(a0.w));
      tilesp[tid + 256] = make_uint4(splitpk(a1.x), splitpk(a1.y), splitpk(a1.z), splitpk(a1.w));
    }
    __syncthreads();
    // threshold refresh (any value ever in sthr is a valid bound)
    threshP = fminf(ld[19], __uint_as_float(sthr[qlocal])) + MARGIN;
    #pragma unroll 4
    for (int g = 0; g < 32; ++g) {
      // A fragment: lane supplies point (g*16+cq), k-slots kg*8..+8
      uint4 s = tilesp[g*16 + cq];
      unsigned int u0 = (kg == 0) ? s.x : s.z;
      unsigned int u2 = (kg == 0) ? s.y : s.w;
      unsigned int u3 = (kg == 0) ? u2 : 0x3F803F80u;
      if (kg >= 2) { u0 = 0; u2 = 0; u3 = 0; }
      FRU afr; afr.u[0] = u0; afr.u[1] = u0; afr.u[2] = u2; afr.u[3] = u3;
      f32x4 dd = __builtin_amdgcn_mfma_f32_16x16x32_bf16(afr.v, bfr.v, zf, 0, 0, 0);
      int pbase = ch*512 + g*16 + kg*4;
      #pragma unroll
      for (int r = 0; r < 4; ++r) {
        if (dd[r] < threshP) {
          stk[cnt*256 + tid] = make_float2(dd[r], __int_as_float(pbase + r));
          cnt++;
        }
      }
      if (__ballot(cnt >= KCAP-3)) KNN_FLUSH();   // cnt grows <=4/group: never overflows
    }
    if (__ballot(cnt > 0)) KNN_FLUSH();           // chunk-end drain (tile still live)
  }

  __syncthreads();                   // scan done; stack region reused as lsd/lsi
  #pragma unroll
  for (int j = 0; j < 20; ++j) { lsd[tid*20 + j] = ld[j]; lsi[tid*20 + j] = li[j]; }
  __syncthreads();

  if (tid < 64) {                    // merger for block-local query tid
    int w2 = tid >> 4, c2 = tid & 15;
    int base = w2*64 + c2;
    int p0 = base*20, p1 = (base+16)*20, p2 = (base+32)*20, p3 = (base+48)*20;
    int i0 = 0, i1 = 0, i2 = 0, i3 = 0;
    int rq = blockIdx.x*64 + tid;
    float4 qq = pf4[rq];
    float dis[20]; int outi[20];
    #pragma unroll
    for (int o = 0; o < 20; ++o) {   // FULL unroll: dis/outi stay in VGPRs
      float d0 = lsd[p0+i0], d1 = lsd[p1+i1], d2v = lsd[p2+i2], d3 = lsd[p3+i3];
      int   j0 = lsi[p0+i0], j1 = lsi[p1+i1], j2  = lsi[p2+i2], j3 = lsi[p3+i3];
      float bd = d0; int bi = j0; int sel = 0;
      if (d1  < bd || (d1  == bd && j1 < bi)) { bd = d1;  bi = j1; sel = 1; }  // global idx tie-break
      if (d2v < bd || (d2v == bd && j2 < bi)) { bd = d2v; bi = j2; sel = 2; }
      if (d3  < bd || (d3  == bd && j3 < bi)) { bd = d3;  bi = j3; sel = 3; }
      i0 += (sel==0); i1 += (sel==1); i2 += (sel==2); i3 += (sel==3);
      dis[o] = sqrtf(fmaxf(bd, 1e-12f));
      outi[o] = bi;
    }
    // ---- fused attention softmax weights, all 6 blocks ----
    float nx[20], ny[20], nz[20];
    #pragma unroll
    for (int k = 0; k < 20; ++k) {   // FULL unroll: nx/ny/nz stay in VGPRs
      idx16[rq*20 + k] = (unsigned short)outi[k];
      float4 pp = pf4[(b << 12) + outi[k]];
      nx[k] = pp.x; ny[k] = pp.y; nz[k] = pp.z;
    }
    for (int i = 0; i < NBK; ++i) {
      float w0 = ldp(Wc,i*7+0,f32m), w1 = ldp(Wc,i*7+1,f32m), w2 = ldp(Wc,i*7+2,f32m);
      float w3 = ldp(Wc,i*7+3,f32m), w4 = ldp(Wc,i*7+4,f32m), w5 = ldp(Wc,i*7+5,f32m);
      float w6 = ldp(Wc,i*7+6,f32m);
      float bci = ldp(bc,i,f32m);
      float s[20]; float mx = -3.0e38f;
      #pragma unroll
      for (int k = 0; k < 20; ++k) {
        float v = bci;
        v = fmaf(dis[k], w0, v);
        v = fmaf(nx[k], w1, v); v = fmaf(ny[k], w2, v); v = fmaf(nz[k], w3, v);
        v = fmaf(qq.x, w4, v);  v = fmaf(qq.y, w5, v);  v = fmaf(qq.z, w6, v);
        s[k] = v; mx = fmaxf(mx, v);
      }
      float sum = 0.f;
      #pragma unroll
      for (int k = 0; k < 20; ++k) { float e = __expf(s[k] - mx); s[k] = e; sum += e; }
      float inv = 1.0f / sum;
      #pragma unroll
      for (int k = 0; k < 20; ++k) wsoftb[(rq*6 + i)*20 + k] = f2b(s[k]*inv);
    }
  }
}

// ---------------- ALL SIX resnet blocks in one persistent kernel ----------------
// R9 k_block body (2048 x 128-thread blocks, 3 intra barriers, descratched
// stage-1) looped 6x with a SOFTWARE grid barrier between iterations (R10's
// hipLaunchCooperativeKernel failed under graph capture; this is a normal,
// capturable launch). Co-residency guaranteed by resources: grid 2048 = 8
// blocks/CU x 256 CUs; __launch_bounds__(128,4) (2 waves/blk, 4 waves/SIMD ->
// 8 blk/CU, VGPR<=128); LDS 8.7KB x 8 = 70KB < 160KB -> CP places all 2048,
// spin cannot deadlock. Barrier: release __threadfence (agent scope: per-XCD
// L2 writeback) -> agent-scope atomicAdd on bar[iblk] -> acquire spin until
// >= 2048 -> acquire __threadfence (L1/L2 invalidate) -> __syncthreads. One
// counter per iteration, zeroed by k_detect each replay (stream-ordered); a
// stale >=2048 counter (standalone rocprof replay) makes barriers pass-through
// - no hang. Math/accumulation order bit-identical to the 6-launch version;
// ping-pong parity (6 iters -> final net in netA).
__global__ __launch_bounds__(128, 4) void k_block6(unsigned short* __restrict__ netA,
                                                   unsigned short* __restrict__ netB,
                                                   const unsigned short* __restrict__ idx16,
                                                   const unsigned short* __restrict__ wsoftb,
                                                   const unsigned short* __restrict__ wT,
                                                   const void* __restrict__ b0s,
                                                   const void* __restrict__ b1s,
                                                   const void* __restrict__ bos,
                                                   const int* __restrict__ flagp,
                                                   unsigned int* __restrict__ bar){
  __shared__ unsigned short ldsA[16*136];
  __shared__ unsigned short ldsH[16*136];
  int tid = threadIdx.x;
  int f32m = *flagp;
  int c = tid >> 6, lane = tid & 63;   // c = col half 0/1
  int b  = blockIdx.x & 7;   // XCD swizzle: gathers stay within one batch's net
  int r0 = (b << 12) + ((blockIdx.x >> 3) << 4);
  int m = lane & 15, qd = lane >> 4;

  #pragma unroll 1
  for (int iblk = 0; iblk < 6; ++iblk) {
    const unsigned short* netIn  = (iblk & 1) ? netB : netA;
    unsigned short*       netOut = (iblk & 1) ? netA : netB;
    int hasResid = (iblk > 0) ? 1 : 0;
    const unsigned short* W0T = wT + iblk*32768;
    const unsigned short* W1T = wT + 196608 + iblk*16384;
    const unsigned short* WsT = wT + 294912 + iblk*32768;
    const unsigned short* WoT = wT + 491520 + iblk*16384;

    // ---- stage 1: attsum[r][cols c*64+cg*16 .. +16] = sum_k w * netIn[idx_k] ----
    {
      int r = lane >> 2, cg2 = lane & 3;
      int grow = r0 + r;
      int cbase = c*64 + cg2*16;
      const unsigned int* ip = (const unsigned int*)(idx16 + grow*20);
      const unsigned int* wp = (const unsigned int*)(wsoftb + (grow*6 + iblk)*20);
      const unsigned short* nbase = netIn + (b << 12)*128 + cbase;
      float acc[16];
      #pragma unroll
      for (int j = 0; j < 16; ++j) acc[j] = 0.f;
      #pragma unroll 2
      for (int kk = 0; kk < 10; ++kk) {
        unsigned int pair  = ip[kk];     // direct pointer load: no private array
        unsigned int wpair = wp[kk];
        int nb0 = (int)(pair & 4095u);
        int nb1 = (int)((pair >> 16) & 4095u);
        float wk0 = lo2f(wpair);
        float wk1 = hi2f(wpair);
        const uint4* np0 = (const uint4*)(nbase + nb0*128);
        const uint4* np1 = (const uint4*)(nbase + nb1*128);
        uint4 a0 = np0[0], b0_ = np0[1];
        uint4 a1 = np1[0], b1_ = np1[1];
        // k = 2kk (wk0):
        acc[0]  = fmaf(wk0, lo2f(a0.x),  acc[0]);
        acc[1]  = fmaf(wk0, hi2f(a0.x),  acc[1]);
        acc[2]  = fmaf(wk0, lo2f(a0.y),  acc[2]);
        acc[3]  = fmaf(wk0, hi2f(a0.y),  acc[3]);
        acc[4]  = fmaf(wk0, lo2f(a0.z),  acc[4]);
        acc[5]  = fmaf(wk0, hi2f(a0.z),  acc[5]);
        acc[6]  = fmaf(wk0, lo2f(a0.w),  acc[6]);
        acc[7]  = fmaf(wk0, hi2f(a0.w),  acc[7]);
        acc[8]  = fmaf(wk0, lo2f(b0_.x), acc[8]);
        acc[9]  = fmaf(wk0, hi2f(b0_.x), acc[9]);
        acc[10] = fmaf(wk0, lo2f(b0_.y), acc[10]);
        acc[11] = fmaf(wk0, hi2f(b0_.y), acc[11]);
        acc[12] = fmaf(wk0, lo2f(b0_.z), acc[12]);
        acc[13] = fmaf(wk0, hi2f(b0_.z), acc[13]);
        acc[14] = fmaf(wk0, lo2f(b0_.w), acc[14]);
        acc[15] = fmaf(wk0, hi2f(b0_.w), acc[15]);
        // k = 2kk+1 (wk1):
        acc[0]  = fmaf(wk1, lo2f(a1.x),  acc[0]);
        acc[1]  = fmaf(wk1, hi2f(a1.x),  acc[1]);
        acc[2]  = fmaf(wk1, lo2f(a1.y),  acc[2]);
        acc[3]  = fmaf(wk1, hi2f(a1.y),  acc[3]);
        acc[4]  = fmaf(wk1, lo2f(a1.z),  acc[4]);
        acc[5]  = fmaf(wk1, hi2f(a1.z),  acc[5]);
        acc[6]  = fmaf(wk1, lo2f(a1.w),  acc[6]);
        acc[7]  = fmaf(wk1, hi2f(a1.w),  acc[7]);
        acc[8]  = fmaf(wk1, lo2f(b1_.x), acc[8]);
        acc[9]  = fmaf(wk1, hi2f(b1_.x), acc[9]);
        acc[10] = fmaf(wk1, lo2f(b1_.y), acc[10]);
        acc[11] = fmaf(wk1, hi2f(b1_.y), acc[11]);
        acc[12] = fmaf(wk1, lo2f(b1_.z), acc[12]);
        acc[13] = fmaf(wk1, hi2f(b1_.z), acc[13]);
        acc[14] = fmaf(wk1, lo2f(b1_.w), acc[14]);
        acc[15] = fmaf(wk1, hi2f(b1_.w), acc[15]);
      }
      #pragma unroll
      for (int j = 0; j < 8; ++j) {
        unsigned int pr = ((unsigned int)f2b(acc[2*j+1]) << 16) | (unsigned int)f2b(acc[2*j]);
        *(unsigned int*)(ldsH + r*136 + cbase + 2*j) = pr;
      }
    }
    __syncthreads();

    // ---- stage 2: att = attsum @ Wo^T + bo -> ldsA (4 col-tiles per wave) ----
    {
      bf16x8 asf[4];
      #pragma unroll
      for (int ks = 0; ks < 4; ++ks)
        asf[ks] = *(const bf16x8*)(ldsH + m*136 + ks*32 + qd*8);
      f32x4 acc2[4];
      #pragma unroll
      for (int i = 0; i < 4; ++i) { f32x4 z = {0.f,0.f,0.f,0.f}; acc2[i] = z; }
      #pragma unroll
      for (int i = 0; i < 4; ++i) {
        int cti = c*4 + i;
        const unsigned short* bp = WoT + (cti*16 + m)*128 + qd*8;
        #pragma unroll
        for (int ks = 0; ks < 4; ++ks)
          acc2[i] = __builtin_amdgcn_mfma_f32_16x16x32_bf16(asf[ks], *(const bf16x8*)(bp + ks*32), acc2[i], 0, 0, 0);
      }
      #pragma unroll
      for (int i = 0; i < 4; ++i) {
        int col = (c*4 + i)*16 + m;
        float bo = ldp(bos, iblk*128 + col, f32m);
        #pragma unroll
        for (int rr = 0; rr < 4; ++rr)
          ldsA[(qd*4 + rr)*136 + col] = f2b(acc2[i][rr] + bo);
      }
    }
    __syncthreads();

    // ---- stage 3: h = relu(net)@W0a + relu(att)@W0b + b0; relu(h) -> ldsH ----
    bf16x8 nf[4], af[4];
    {
      const unsigned short* nrow = netIn + (r0 + m)*128;
      #pragma unroll
      for (int ks = 0; ks < 4; ++ks) nf[ks] = *(const bf16x8*)(nrow + ks*32 + qd*8);
      #pragma unroll
      for (int ks = 0; ks < 4; ++ks) af[ks] = *(const bf16x8*)(ldsA + m*136 + ks*32 + qd*8);
      bf16x8 rnf[4], raf[4];
      #pragma unroll
      for (int ks = 0; ks < 4; ++ks) { rnf[ks] = relu8(nf[ks]); raf[ks] = relu8(af[ks]); }
      f32x4 acc3[4];
      #pragma unroll
      for (int i = 0; i < 4; ++i) { f32x4 z = {0.f,0.f,0.f,0.f}; acc3[i] = z; }
      #pragma unroll
      for (int i = 0; i < 4; ++i) {
        int cti = c*4 + i;
        const unsigned short* bp = W0T + (cti*16 + m)*256 + qd*8;
        #pragma unroll
        for (int ks = 0; ks < 4; ++ks)
          acc3[i] = __builtin_amdgcn_mfma_f32_16x16x32_bf16(rnf[ks], *(const bf16x8*)(bp + ks*32), acc3[i], 0, 0, 0);
        #pragma unroll
        for (int ks = 0; ks < 4; ++ks)
          acc3[i] = __builtin_amdgcn_mfma_f32_16x16x32_bf16(raf[ks], *(const bf16x8*)(bp + 128 + ks*32), acc3[i], 0, 0, 0);
      }
      #pragma unroll
      for (int i = 0; i < 4; ++i) {
        int col = (c*4 + i)*16 + m;
        float b0v = ldp(b0s, iblk*128 + col, f32m);
        #pragma unroll
        for (int rr = 0; rr < 4; ++rr)
          ldsH[(qd*4 + rr)*136 + col] = f2b(fmaxf(acc3[i][rr] + b0v, 0.f));
      }
    }
    __syncthreads();

    // ---- stage 4: out = relu(h)@W1 + b1 + net@Wsa + att@Wsb (+ resid) ----
    {
      bf16x8 hf[4];
      #pragma unroll
      for (int ks = 0; ks < 4; ++ks) hf[ks] = *(const bf16x8*)(ldsH + m*136 + ks*32 + qd*8);
      f32x4 acc4[4];
      #pragma unroll
      for (int i = 0; i < 4; ++i) { f32x4 z = {0.f,0.f,0.f,0.f}; acc4[i] = z; }
      #pragma unroll
      for (int i = 0; i < 4; ++i) {
        int cti = c*4 + i;
        const unsigned short* bp1 = W1T + (cti*16 + m)*128 + qd*8;
        #pragma unroll
        for (int ks = 0; ks < 4; ++ks)
          acc4[i] = __builtin_amdgcn_mfma_f32_16x16x32_bf16(hf[ks], *(const bf16x8*)(bp1 + ks*32), acc4[i], 0, 0, 0);
        const unsigned short* bps = WsT + (cti*16 + m)*256 + qd*8;
        #pragma unroll
        for (int ks = 0; ks < 4; ++ks)
          acc4[i] = __builtin_amdgcn_mfma_f32_16x16x32_bf16(nf[ks], *(const bf16x8*)(bps + ks*32), acc4[i], 0, 0, 0);
        #pragma unroll
        for (int ks = 0; ks < 4; ++ks)
          acc4[i] = __builtin_amdgcn_mfma_f32_16x16x32_bf16(af[ks], *(const bf16x8*)(bps + 128 + ks*32), acc4[i], 0, 0, 0);
      }
      #pragma unroll
      for (int i = 0; i < 4; ++i) {
        int col = (c*4 + i)*16 + m;
        float b1v = ldp(b1s, iblk*128 + col, f32m);
        #pragma unroll
        for (int rr = 0; rr < 4; ++rr) {
          int grow2 = r0 + qd*4 + rr;
          float v = acc4[i][rr] + b1v;
          if (hasResid) v += b2f(netIn[grow2*128 + col]);
          netOut[grow2*128 + col] = f2b(v);
        }
      }
    }

    // ---- software grid barrier: next iteration gathers this one's output ----
    if (iblk < 5) {
      __syncthreads();
      if (tid == 0) {
        __threadfence();   // release: write back this block's stores (per-XCD L2 -> coherent point)
        __hip_atomic_fetch_add(&bar[iblk], 1u, __ATOMIC_ACQ_REL, __HIP_MEMORY_SCOPE_AGENT);
        while (__hip_atomic_load(&bar[iblk], __ATOMIC_ACQUIRE, __HIP_MEMORY_SCOPE_AGENT) < 2048u) {
          __builtin_amdgcn_s_sleep(8);
        }
        __threadfence();   // acquire: invalidate L1/L2 so gathers see other XCDs' writes
      }
      __syncthreads();
    }
  }
}

// ---------------- final: out = net @ W_c + b_c (dtype per flag) ----------------
__global__ __launch_bounds__(256) void k_final(const unsigned short* __restrict__ netIn,
                                               const unsigned short* __restrict__ WcT,
                                               const void* __restrict__ bcv,
                                               const int* __restrict__ flagp,
                                               void* __restrict__ out){
  int tid = threadIdx.x; int w = tid >> 6, lane = tid & 63;
  int f32m = *flagp;
  int t = w >> 1, c = w & 1;
  int r0 = blockIdx.x*32 + t*16;
  int m = lane & 15, qd = lane >> 4;
  bf16x8 nf[4];
  #pragma unroll
  for (int ks = 0; ks < 4; ++ks)
    nf[ks] = *(const bf16x8*)(netIn + (r0 + m)*128 + ks*32 + qd*8);
  f32x4 acc[4];
  #pragma unroll
  for (int i = 0; i < 4; ++i) { f32x4 z = {0.f,0.f,0.f,0.f}; acc[i] = z; }
  #pragma unroll
  for (int i = 0; i < 4; ++i) {
    int cti = c*4 + i;
    const unsigned short* bp = WcT + (cti*16 + m)*128 + qd*8;
    #pragma unroll
    for (int ks = 0; ks < 4; ++ks)
      acc[i] = __builtin_amdgcn_mfma_f32_16x16x32_bf16(nf[ks], *(const bf16x8*)(bp + ks*32), acc[i], 0, 0, 0);
  }
  if (f32m) {
    float* o = (float*)out;
    #pragma unroll
    for (int i = 0; i < 4; ++i) {
      int col = (c*4 + i)*16 + m;
      float bcf = ldp(bcv, col, 1);
      #pragma unroll
      for (int rr = 0; rr < 4; ++rr)
        o[(r0 + qd*4 + rr)*128 + col] = acc[i][rr] + bcf;
    }
  } else {
    unsigned short* o = (unsigned short*)out;
    #pragma unroll
    for (int i = 0; i < 4; ++i) {
      int col = (c*4 + i)*16 + m;
      float bcf = ldp(bcv, col, 0);
      #pragma unroll
      for (int rr = 0; rr < 4; ++rr)
        o[(r0 + qd*4 + rr)*128 + col] = f2b(acc[i][rr] + bcf);
    }
  }
}

// ---------------- host launch ----------------
extern "C" void kernel_launch(void* const* d_in, const int* in_sizes, int n_in,
                              void* d_out, int out_size, void* d_ws, size_t ws_size,
                              hipStream_t stream){
  const void* p    = d_in[0];
  const void* Wpos = d_in[1];
  const void* bpos = d_in[2];
  const void* W0   = d_in[3];
  const void* b0   = d_in[4];
  const void* W1   = d_in[5];
  const void* b1   = d_in[6];
  const void* Ws   = d_in[7];
  const void* Wc_  = d_in[8];
  const void* bc_  = d_in[9];
  const void* Wo   = d_in[10];
  const void* bo   = d_in[11];
  const void* WC   = d_in[12];
  const void* bC   = d_in[13];

  char* ws = (char*)d_ws;
  int*            flag   = (int*)(ws + 0);                    //      4 B
  unsigned int*   bar    = (unsigned int*)(ws + 128);         //     32 B (grid-barrier counters)
  float4*         pf4    = (float4*)(ws + 256);               //   524288 B
  unsigned short* idx16  = (unsigned short*)(ws + 524544);    //  1310720 B
  unsigned short* wsoftb = (unsigned short*)(ws + 1835264);   //  7864320 B
  unsigned short* netA   = (unsigned short*)(ws + 9699584);   //  8388608 B
  unsigned short* wT     = (unsigned short*)(ws + 18088192);  //  1212416 B (total ~19.3 MB)

  k_detect     <<<dim3(1),     dim3(64),  0, stream>>>((const unsigned short*)Wpos, flag, bar);
  k_prep_points<<<dim3(128),   dim3(256), 0, stream>>>(p, flag, pf4);
  k_net0       <<<dim3(16384), dim3(256), 0, stream>>>(pf4, Wpos, bpos, flag, netA);
  k_transpose  <<<dim3(2368),  dim3(256), 0, stream>>>(W0, W1, Ws, Wo, WC, flag, wT);
  k_knn        <<<dim3(512),   dim3(256), 0, stream>>>(pf4, Wc_, bc_, flag, idx16, wsoftb);

  // all six resnet blocks in one persistent kernel (final net -> netA)
  {
    unsigned short* netB = (unsigned short*)d_out;   // d_out as bf16 ping-pong scratch
    k_block6<<<dim3(2048), dim3(128), 0, stream>>>(netA, netB, idx16, wsoftb, wT,
                                                   b0, b1, bo, flag, bar);
  }
  k_final<<<dim3(1024), dim3(256), 0, stream>>>(netA, wT + 589824, bC, flag, d_out);
}

// Round 12
// 605.774 us; speedup vs baseline: 3.7579x; 3.7579x over previous
//
#include <hip/hip_runtime.h>
#include <hip/hip_bf16.h>
#include <math.h>

#define BB 8
#define TT 4096
#define HHD 128
#define NBK 6
#define KNN 20
#define BT (BB*TT)

typedef __attribute__((ext_vector_type(8))) short bf16x8;
typedef __attribute__((ext_vector_type(4))) float f32x4;

__device__ __forceinline__ float b2f(unsigned short u){
  return __uint_as_float(((unsigned int)u) << 16);
}
__device__ __forceinline__ unsigned short f2b(float f){
  unsigned int x = __float_as_uint(f);
  unsigned int r = (x + 0x7fffu + ((x >> 16) & 1u)) >> 16;   // RTNE
  return (unsigned short)r;
}
// dtype-agnostic parameter load: f32m=1 -> buffer is float32, else bf16
__device__ __forceinline__ float ldp(const void* base, int i, int f32m){
  return f32m ? ((const float*)base)[i] : b2f(((const unsigned short*)base)[i]);
}
__device__ __forceinline__ float lo2f(unsigned int u){ return __uint_as_float(u << 16); }
__device__ __forceinline__ float hi2f(unsigned int u){ return __uint_as_float(u & 0xffff0000u); }
__device__ __forceinline__ unsigned int relu2(unsigned int u){
  unsigned int s = u & 0x80008000u;
  unsigned int m = s | (s - (s >> 15));
  return u & ~m;
}
__device__ __forceinline__ bf16x8 relu8(bf16x8 x){
  union { bf16x8 v; unsigned int u[4]; } t; t.v = x;
  t.u[0] = relu2(t.u[0]); t.u[1] = relu2(t.u[1]);
  t.u[2] = relu2(t.u[2]); t.u[3] = relu2(t.u[3]);
  return t.v;
}
// two-term bf16 split of fp32 v, packed (hi | lo<<16). v = hi + lo + res,
// |res| <= 2^-17 |v| (Sterbenz: v - b2f(hi) exact, then RTNE to bf16).
__device__ __forceinline__ unsigned int splitpk(float v){
  unsigned short h = f2b(v);
  float hv = b2f(h);
  unsigned short l = f2b(v - hv);
  return (unsigned int)h | ((unsigned int)l << 16);
}

// ---------------- dtype detector (64-lane parallel) ----------------
__global__ void k_detect(const unsigned short* __restrict__ wpos_raw, int* __restrict__ flag){
  int lane = threadIdx.x;   // 64 threads
  int cnt = 0;
  for (int i = lane; i < 384; i += 64) {
    unsigned int e = (wpos_raw[i] >> 7) & 0xFFu;
    if (e >= 0x90u) cnt++;
  }
  #pragma unroll
  for (int off = 32; off > 0; off >>= 1) cnt += __shfl_down(cnt, off);
  if (lane == 0) *flag = (cnt > 10) ? 1 : 0;
}

// ---------------- prep: p -> float4 (x,y,z,|p|^2) ----------------
__global__ __launch_bounds__(256) void k_prep_points(const void* __restrict__ p,
                                                     const int* __restrict__ flagp,
                                                     float4* __restrict__ pf4){
  int r = blockIdx.x*256 + threadIdx.x;
  if (r >= BT) return;
  int f32m = *flagp;
  float x = ldp(p, r*3+0, f32m), y = ldp(p, r*3+1, f32m), z = ldp(p, r*3+2, f32m);
  float sq = __fadd_rn(__fadd_rn(__fmul_rn(x,x), __fmul_rn(y,y)), __fmul_rn(z,z));
  pf4[r] = make_float4(x, y, z, sq);
}

// ---------------- net0 = p @ W_pos + b_pos  (bf16 out) ----------------
__global__ __launch_bounds__(256) void k_net0(const float4* __restrict__ pf4,
                                              const void* __restrict__ Wpos,
                                              const void* __restrict__ bpos,
                                              const int* __restrict__ flagp,
                                              unsigned short* __restrict__ netA){
  int t = blockIdx.x*256 + threadIdx.x;   // over BT*128
  int f32m = *flagp;
  int c = t & 127, r = t >> 7;
  float4 q = pf4[r];
  float v = ldp(bpos, c, f32m);
  v = fmaf(q.x, ldp(Wpos, c,       f32m), v);
  v = fmaf(q.y, ldp(Wpos, 128 + c, f32m), v);
  v = fmaf(q.z, ldp(Wpos, 256 + c, f32m), v);
  netA[t] = f2b(v);
}

// ---------------- transpose all weights to [N][K] bf16 ----------------
// layout in wT (shorts): W0T 6*32768 | W1T 6*16384 | WsT 6*32768 | WoT 6*16384 | WcT 16384
__global__ __launch_bounds__(256) void k_transpose(const void* __restrict__ W0,
                                                   const void* __restrict__ W1,
                                                   const void* __restrict__ Ws,
                                                   const void* __restrict__ Wo,
                                                   const void* __restrict__ Wc,
                                                   const int* __restrict__ flagp,
                                                   unsigned short* __restrict__ wT){
  int t = blockIdx.x*256 + threadIdx.x;
  int f32m = *flagp;
  if (t < 196608) {                    // W0T: per block [128][256]
    int i = t >> 15; int rem = t & 32767; int n = rem >> 8; int k = rem & 255;
    wT[t] = f2b(ldp(W0, i*32768 + k*128 + n, f32m));
  } else if (t < 294912) {             // W1T: [128][128]
    int u = t - 196608; int i = u >> 14; int rem = u & 16383; int n = rem >> 7; int k = rem & 127;
    wT[t] = f2b(ldp(W1, i*16384 + k*128 + n, f32m));
  } else if (t < 491520) {             // WsT: [128][256]
    int u = t - 294912; int i = u >> 15; int rem = u & 32767; int n = rem >> 8; int k = rem & 255;
    wT[t] = f2b(ldp(Ws, i*32768 + k*128 + n, f32m));
  } else if (t < 589824) {             // WoT: [128][128]
    int u = t - 491520; int i = u >> 14; int rem = u & 16383; int n = rem >> 7; int k = rem & 127;
    wT[t] = f2b(ldp(Wo, i*16384 + k*128 + n, f32m));
  } else if (t < 606208) {             // WcT: [128][128]
    int u = t - 589824; int n = u >> 7; int k = u & 127;
    wT[t] = f2b(ldp(Wc, k*128 + n, f32m));
  }
}

// sorted ascending insert into (ld,li)[20], strict '<' keeps earliest index on ties
#define INS(act, dv, iv) do { bool A_ = (act); float D_ = (dv); int I_ = (iv);        \
  _Pragma("unroll")                                                                    \
  for (int j = 19; j >= 1; --j) {                                                      \
    bool cj = A_ && (D_ < ld[j]); bool cm = A_ && (D_ < ld[j-1]);                      \
    ld[j] = cj ? (cm ? ld[j-1] : D_) : ld[j];                                          \
    li[j] = cj ? (cm ? li[j-1] : I_) : li[j];                                          \
  }                                                                                    \
  { bool c0 = A_ && (D_ < ld[0]); ld[0] = c0 ? D_ : ld[0]; li[0] = c0 ? I_ : li[0]; } \
} while(0)

#define KCAP   20       // admission stack depth (float2, slot-major)
#define MARGIN 0.02f    // > worst-case MFMA-d2 error (~5e-3); filter-only, exact recompute follows

// batched exact-recompute + sorted-insert flush. All stacked entries are from
// the CURRENT chunk (we flush at every chunk end), so exact d2 is recomputed
// from the live float4 tile with the bit-identical R2 formula.
#define KNN_FLUSH() do {                                                               \
  int mc_ = cnt;                                                                       \
  _Pragma("unroll")                                                                    \
  for (int o_ = 32; o_ > 0; o_ >>= 1) { int t_ = __shfl_xor(mc_, o_); mc_ = mc_ > t_ ? mc_ : t_; } \
  _Pragma("unroll 1")                                                                  \
  for (int u_ = 0; u_ < mc_; ++u_) {                                                   \
    float2 e_ = stk[u_*256 + tid];                                                     \
    bool act_ = u_ < cnt;                                                              \
    int piv_ = __float_as_int(e_.y);                                                   \
    float4 pp_ = tilef4[act_ ? (piv_ - ch*512) : 0];                                   \
    float dot_ = __fadd_rn(__fadd_rn(__fmul_rn(q.x,pp_.x), __fmul_rn(q.y,pp_.y)),      \
                           __fmul_rn(q.z,pp_.z));                                      \
    float d2e_ = __fsub_rn(__fadd_rn(q.w, pp_.w), __fmul_rn(2.0f, dot_));              \
    INS(act_, d2e_, piv_);                                                             \
  }                                                                                    \
  cnt = 0;                                                                             \
  atomicMin(&sthr[qlocal], __float_as_uint(fmaxf(ld[19], 0.0f)));                      \
  threshP = fminf(ld[19], __uint_as_float(sthr[qlocal])) + MARGIN;                     \
} while(0)

// ---------------- KNN: MFMA-filtered scan, 4 waves / 64 queries ----------------
// Proven 174us version (R6/R9). Untouched.
__global__ __launch_bounds__(256) void k_knn(const float4* __restrict__ pf4,
                                             const void* __restrict__ Wc,
                                             const void* __restrict__ bc,
                                             const int* __restrict__ flagp,
                                             unsigned short* __restrict__ idx16,
                                             unsigned short* __restrict__ wsoftb){
  // scan:  tilef4 [0,8192) | tilesp [8192,16384) | stk [16384,57344)
  // merge: lsd [16384,36864) | lsi [36864,57344)   (overlay, stacks dead)
  __shared__ __align__(16) char smem[57344];
  __shared__ unsigned int sthr[64];              // per-query shared threshold (float bits)
  float4* tilef4 = (float4*)smem;                // [512] original coords (exact recompute)
  uint4*  tilesp = (uint4*)(smem + 8192);        // [512] packed hi/lo splits (MFMA A source)
  float2* stk    = (float2*)(smem + 16384);      // [KCAP][256] (d2approx, idx-bits)
  float*  lsd    = (float*)(smem + 16384);       // [256][20] (merge phase)
  int*    lsi    = (int*)(smem + 36864);         // [256][20] (merge phase)

  int tid  = threadIdx.x;
  int wv   = tid >> 6, lane = tid & 63;
  int cq   = lane & 15;          // query column within wave
  int kg   = lane >> 4;          // k-group for A/B supply; merge partition for D rows
  int qlocal = wv*16 + cq;       // block-local query 0..63
  int b    = blockIdx.x >> 6;    // batch (64 blocks of 64 queries per batch)
  int f32m = *flagp;
  float4 q = pf4[blockIdx.x*64 + qlocal];

  if (tid < 64) sthr[tid] = 0x7F7FFFFFu;         // +3.4e38

  // B fragment (queries) built once: lane supplies query cq, k-slots kg*8..+8
  union FRU { bf16x8 v; unsigned int u[4]; };
  FRU bfr;
  {
    float e = (kg == 0) ? -2.0f*q.x : -2.0f*q.z;
    unsigned int ehl = splitpk(e);
    unsigned int eh = ehl & 0xffffu, el = ehl >> 16;
    float f = (kg == 0) ? -2.0f*q.y : q.w;
    unsigned int fhl = splitpk(f);
    unsigned int fh = fhl & 0xffffu, fl = fhl >> 16;
    unsigned int v0 = eh | (eh << 16);
    unsigned int v1 = el | (el << 16);
    unsigned int v2 = (kg == 0) ? (fh | (fh << 16)) : 0x3F803F80u;
    unsigned int v3 = (kg == 0) ? (fl | (fl << 16)) : fhl;
    if (kg >= 2) { v0 = 0; v1 = 0; v2 = 0; v3 = 0; }
    bfr.u[0] = v0; bfr.u[1] = v1; bfr.u[2] = v2; bfr.u[3] = v3;
  }
  const f32x4 zf = {0.f, 0.f, 0.f, 0.f};

  float ld[20]; int li[20];
  #pragma unroll
  for (int j = 0; j < 20; ++j) { ld[j] = 3.0e38f; li[j] = 0; }
  float threshP = 3.0e38f;
  int cnt = 0;

  for (int ch = 0; ch < 8; ++ch) {
    __syncthreads();
    {   // stage 512 points: float4 tile + split tile
      const float4* src = pf4 + (b << 12) + ch*512;
      float4 a0 = src[tid], a1 = src[tid + 256];
      tilef4[tid]       = a0;
      tilef4[tid + 256] = a1;
      tilesp[tid]       = make_uint4(splitpk(a0.x), splitpk(a0.y), splitpk(a0.z), splitpk(a0.w));
      tilesp[tid + 256] = make_uint4(splitpk(a1.x), splitpk(a1.y), splitpk(a1.z), splitpk(a1.w));
    }
    __syncthreads();
    // threshold refresh (any value ever in sthr is a valid bound)
    threshP = fminf(ld[19], __uint_as_float(sthr[qlocal])) + MARGIN;
    #pragma unroll 4
    for (int g = 0; g < 32; ++g) {
      // A fragment: lane supplies point (g*16+cq), k-slots kg*8..+8
      uint4 s = tilesp[g*16 + cq];
      unsigned int u0 = (kg == 0) ? s.x : s.z;
      unsigned int u2 = (kg == 0) ? s.y : s.w;
      unsigned int u3 = (kg == 0) ? u2 : 0x3F803F80u;
      if (kg >= 2) { u0 = 0; u2 = 0; u3 = 0; }
      FRU afr; afr.u[0] = u0; afr.u[1] = u0; afr.u[2] = u2; afr.u[3] = u3;
      f32x4 dd = __builtin_amdgcn_mfma_f32_16x16x32_bf16(afr.v, bfr.v, zf, 0, 0, 0);
      int pbase = ch*512 + g*16 + kg*4;
      #pragma unroll
      for (int r = 0; r < 4; ++r) {
        if (dd[r] < threshP) {
          stk[cnt*256 + tid] = make_float2(dd[r], __int_as_float(pbase + r));
          cnt++;
        }
      }
      if (__ballot(cnt >= KCAP-3)) KNN_FLUSH();   // cnt grows <=4/group: never overflows
    }
    if (__ballot(cnt > 0)) KNN_FLUSH();           // chunk-end drain (tile still live)
  }

  __syncthreads();                   // scan done; stack region reused as lsd/lsi
  #pragma unroll
  for (int j = 0; j < 20; ++j) { lsd[tid*20 + j] = ld[j]; lsi[tid*20 + j] = li[j]; }
  __syncthreads();

  if (tid < 64) {                    // merger for block-local query tid
    int w2 = tid >> 4, c2 = tid & 15;
    int base = w2*64 + c2;
    int p0 = base*20, p1 = (base+16)*20, p2 = (base+32)*20, p3 = (base+48)*20;
    int i0 = 0, i1 = 0, i2 = 0, i3 = 0;
    int rq = blockIdx.x*64 + tid;
    float4 qq = pf4[rq];
    float dis[20]; int outi[20];
    #pragma unroll
    for (int o = 0; o < 20; ++o) {   // FULL unroll: dis/outi stay in VGPRs
      float d0 = lsd[p0+i0], d1 = lsd[p1+i1], d2v = lsd[p2+i2], d3 = lsd[p3+i3];
      int   j0 = lsi[p0+i0], j1 = lsi[p1+i1], j2  = lsi[p2+i2], j3 = lsi[p3+i3];
      float bd = d0; int bi = j0; int sel = 0;
      if (d1  < bd || (d1  == bd && j1 < bi)) { bd = d1;  bi = j1; sel = 1; }  // global idx tie-break
      if (d2v < bd || (d2v == bd && j2 < bi)) { bd = d2v; bi = j2; sel = 2; }
      if (d3  < bd || (d3  == bd && j3 < bi)) { bd = d3;  bi = j3; sel = 3; }
      i0 += (sel==0); i1 += (sel==1); i2 += (sel==2); i3 += (sel==3);
      dis[o] = sqrtf(fmaxf(bd, 1e-12f));
      outi[o] = bi;
    }
    // ---- fused attention softmax weights, all 6 blocks ----
    float nx[20], ny[20], nz[20];
    #pragma unroll
    for (int k = 0; k < 20; ++k) {   // FULL unroll: nx/ny/nz stay in VGPRs
      idx16[rq*20 + k] = (unsigned short)outi[k];
      float4 pp = pf4[(b << 12) + outi[k]];
      nx[k] = pp.x; ny[k] = pp.y; nz[k] = pp.z;
    }
    for (int i = 0; i < NBK; ++i) {
      float w0 = ldp(Wc,i*7+0,f32m), w1 = ldp(Wc,i*7+1,f32m), w2 = ldp(Wc,i*7+2,f32m);
      float w3 = ldp(Wc,i*7+3,f32m), w4 = ldp(Wc,i*7+4,f32m), w5 = ldp(Wc,i*7+5,f32m);
      float w6 = ldp(Wc,i*7+6,f32m);
      float bci = ldp(bc,i,f32m);
      float s[20]; float mx = -3.0e38f;
      #pragma unroll
      for (int k = 0; k < 20; ++k) {
        float v = bci;
        v = fmaf(dis[k], w0, v);
        v = fmaf(nx[k], w1, v); v = fmaf(ny[k], w2, v); v = fmaf(nz[k], w3, v);
        v = fmaf(qq.x, w4, v);  v = fmaf(qq.y, w5, v);  v = fmaf(qq.z, w6, v);
        s[k] = v; mx = fmaxf(mx, v);
      }
      float sum = 0.f;
      #pragma unroll
      for (int k = 0; k < 20; ++k) { float e = __expf(s[k] - mx); s[k] = e; sum += e; }
      float inv = 1.0f / sum;
      #pragma unroll
      for (int k = 0; k < 20; ++k) wsoftb[(rq*6 + i)*20 + k] = f2b(s[k]*inv);
    }
  }
}

// ---------------- one resnet block (fused gather+attention+GEMMs) ----------------
// R9-proven structure (2048 x 128-thread blocks, descratched stage-1, 6
// serial dispatches — R11 proved software grid barriers cost ~320us each from
// per-XCD L2 invalidate storms, so multi-dispatch stays). NEW (R11 counters:
// WRITE_SIZE 2.1x actual output = partial-line RMW from scattered 2-B stores):
// stage 4 stages acc+b1 as f32 in ldsF, then a coalesced epilogue does the
// residual add + RTNE pack with 32B-contiguous loads/stores per lane (8 lanes
// cover a 256-B row exactly). fp32 op order identical -> bit-identical output.
__global__ __launch_bounds__(128) void k_block(const unsigned short* __restrict__ netIn,
                                               unsigned short* __restrict__ netOut,
                                               const unsigned short* __restrict__ idx16,
                                               const unsigned short* __restrict__ wsoftb,
                                               const unsigned short* __restrict__ wT,
                                               const void* __restrict__ b0s,
                                               const void* __restrict__ b1s,
                                               const void* __restrict__ bos,
                                               const int* __restrict__ flagp,
                                               int iblk, int hasResid){
  __shared__ unsigned short ldsA[16*136];
  __shared__ unsigned short ldsH[16*136];
  __shared__ float ldsF[16*132];       // f32 output staging (+4 pad/row)
  int tid = threadIdx.x;
  int f32m = *flagp;
  int c = tid >> 6, lane = tid & 63;   // c = col half 0/1
  int b  = blockIdx.x & 7;   // XCD swizzle: gathers stay within one batch's net
  int r0 = (b << 12) + ((blockIdx.x >> 3) << 4);
  const unsigned short* W0T = wT + iblk*32768;
  const unsigned short* W1T = wT + 196608 + iblk*16384;
  const unsigned short* WsT = wT + 294912 + iblk*32768;
  const unsigned short* WoT = wT + 491520 + iblk*16384;
  int m = lane & 15, qd = lane >> 4;

  // ---- stage 1: attsum[r][cols c*64+cg*16 .. +16] = sum_k w * netIn[idx_k] ----
  {
    int r = lane >> 2, cg = lane & 3;
    int grow = r0 + r;
    int cbase = c*64 + cg*16;
    const unsigned int* ip = (const unsigned int*)(idx16 + grow*20);
    const unsigned int* wp = (const unsigned int*)(wsoftb + (grow*6 + iblk)*20);
    const unsigned short* nbase = netIn + (b << 12)*128 + cbase;
    float acc[16];
    #pragma unroll
    for (int j = 0; j < 16; ++j) acc[j] = 0.f;
    #pragma unroll 2
    for (int kk = 0; kk < 10; ++kk) {
      unsigned int pair  = ip[kk];     // direct pointer load: no private array
      unsigned int wpair = wp[kk];
      int nb0 = (int)(pair & 4095u);
      int nb1 = (int)((pair >> 16) & 4095u);
      float wk0 = lo2f(wpair);
      float wk1 = hi2f(wpair);
      const uint4* np0 = (const uint4*)(nbase + nb0*128);
      const uint4* np1 = (const uint4*)(nbase + nb1*128);
      uint4 a0 = np0[0], b0_ = np0[1];
      uint4 a1 = np1[0], b1_ = np1[1];
      // k = 2kk (wk0):
      acc[0]  = fmaf(wk0, lo2f(a0.x),  acc[0]);
      acc[1]  = fmaf(wk0, hi2f(a0.x),  acc[1]);
      acc[2]  = fmaf(wk0, lo2f(a0.y),  acc[2]);
      acc[3]  = fmaf(wk0, hi2f(a0.y),  acc[3]);
      acc[4]  = fmaf(wk0, lo2f(a0.z),  acc[4]);
      acc[5]  = fmaf(wk0, hi2f(a0.z),  acc[5]);
      acc[6]  = fmaf(wk0, lo2f(a0.w),  acc[6]);
      acc[7]  = fmaf(wk0, hi2f(a0.w),  acc[7]);
      acc[8]  = fmaf(wk0, lo2f(b0_.x), acc[8]);
      acc[9]  = fmaf(wk0, hi2f(b0_.x), acc[9]);
      acc[10] = fmaf(wk0, lo2f(b0_.y), acc[10]);
      acc[11] = fmaf(wk0, hi2f(b0_.y), acc[11]);
      acc[12] = fmaf(wk0, lo2f(b0_.z), acc[12]);
      acc[13] = fmaf(wk0, hi2f(b0_.z), acc[13]);
      acc[14] = fmaf(wk0, lo2f(b0_.w), acc[14]);
      acc[15] = fmaf(wk0, hi2f(b0_.w), acc[15]);
      // k = 2kk+1 (wk1):
      acc[0]  = fmaf(wk1, lo2f(a1.x),  acc[0]);
      acc[1]  = fmaf(wk1, hi2f(a1.x),  acc[1]);
      acc[2]  = fmaf(wk1, lo2f(a1.y),  acc[2]);
      acc[3]  = fmaf(wk1, hi2f(a1.y),  acc[3]);
      acc[4]  = fmaf(wk1, lo2f(a1.z),  acc[4]);
      acc[5]  = fmaf(wk1, hi2f(a1.z),  acc[5]);
      acc[6]  = fmaf(wk1, lo2f(a1.w),  acc[6]);
      acc[7]  = fmaf(wk1, hi2f(a1.w),  acc[7]);
      acc[8]  = fmaf(wk1, lo2f(b1_.x), acc[8]);
      acc[9]  = fmaf(wk1, hi2f(b1_.x), acc[9]);
      acc[10] = fmaf(wk1, lo2f(b1_.y), acc[10]);
      acc[11] = fmaf(wk1, hi2f(b1_.y), acc[11]);
      acc[12] = fmaf(wk1, lo2f(b1_.z), acc[12]);
      acc[13] = fmaf(wk1, hi2f(b1_.z), acc[13]);
      acc[14] = fmaf(wk1, lo2f(b1_.w), acc[14]);
      acc[15] = fmaf(wk1, hi2f(b1_.w), acc[15]);
    }
    #pragma unroll
    for (int j = 0; j < 8; ++j) {
      unsigned int pr = ((unsigned int)f2b(acc[2*j+1]) << 16) | (unsigned int)f2b(acc[2*j]);
      *(unsigned int*)(ldsH + r*136 + cbase + 2*j) = pr;
    }
  }
  __syncthreads();

  // ---- stage 2: att = attsum @ Wo^T + bo -> ldsA (4 col-tiles per wave) ----
  {
    bf16x8 asf[4];
    #pragma unroll
    for (int ks = 0; ks < 4; ++ks)
      asf[ks] = *(const bf16x8*)(ldsH + m*136 + ks*32 + qd*8);
    f32x4 acc2[4];
    #pragma unroll
    for (int i = 0; i < 4; ++i) { f32x4 z = {0.f,0.f,0.f,0.f}; acc2[i] = z; }
    #pragma unroll
    for (int i = 0; i < 4; ++i) {
      int cti = c*4 + i;
      const unsigned short* bp = WoT + (cti*16 + m)*128 + qd*8;
      #pragma unroll
      for (int ks = 0; ks < 4; ++ks)
        acc2[i] = __builtin_amdgcn_mfma_f32_16x16x32_bf16(asf[ks], *(const bf16x8*)(bp + ks*32), acc2[i], 0, 0, 0);
    }
    #pragma unroll
    for (int i = 0; i < 4; ++i) {
      int col = (c*4 + i)*16 + m;
      float bo = ldp(bos, iblk*128 + col, f32m);
      #pragma unroll
      for (int rr = 0; rr < 4; ++rr)
        ldsA[(qd*4 + rr)*136 + col] = f2b(acc2[i][rr] + bo);
    }
  }
  __syncthreads();

  // ---- stage 3: h = relu(net)@W0a + relu(att)@W0b + b0; relu(h) -> ldsH ----
  bf16x8 nf[4], af[4];
  {
    const unsigned short* nrow = netIn + (r0 + m)*128;
    #pragma unroll
    for (int ks = 0; ks < 4; ++ks) nf[ks] = *(const bf16x8*)(nrow + ks*32 + qd*8);
    #pragma unroll
    for (int ks = 0; ks < 4; ++ks) af[ks] = *(const bf16x8*)(ldsA + m*136 + ks*32 + qd*8);
    bf16x8 rnf[4], raf[4];
    #pragma unroll
    for (int ks = 0; ks < 4; ++ks) { rnf[ks] = relu8(nf[ks]); raf[ks] = relu8(af[ks]); }
    f32x4 acc3[4];
    #pragma unroll
    for (int i = 0; i < 4; ++i) { f32x4 z = {0.f,0.f,0.f,0.f}; acc3[i] = z; }
    #pragma unroll
    for (int i = 0; i < 4; ++i) {
      int cti = c*4 + i;
      const unsigned short* bp = W0T + (cti*16 + m)*256 + qd*8;
      #pragma unroll
      for (int ks = 0; ks < 4; ++ks)
        acc3[i] = __builtin_amdgcn_mfma_f32_16x16x32_bf16(rnf[ks], *(const bf16x8*)(bp + ks*32), acc3[i], 0, 0, 0);
      #pragma unroll
      for (int ks = 0; ks < 4; ++ks)
        acc3[i] = __builtin_amdgcn_mfma_f32_16x16x32_bf16(raf[ks], *(const bf16x8*)(bp + 128 + ks*32), acc3[i], 0, 0, 0);
    }
    #pragma unroll
    for (int i = 0; i < 4; ++i) {
      int col = (c*4 + i)*16 + m;
      float b0v = ldp(b0s, iblk*128 + col, f32m);
      #pragma unroll
      for (int rr = 0; rr < 4; ++rr)
        ldsH[(qd*4 + rr)*136 + col] = f2b(fmaxf(acc3[i][rr] + b0v, 0.f));
    }
  }
  __syncthreads();

  // ---- stage 4: out = relu(h)@W1 + b1 + net@Wsa + att@Wsb; stage f32 in ldsF ----
  {
    bf16x8 hf[4];
    #pragma unroll
    for (int ks = 0; ks < 4; ++ks) hf[ks] = *(const bf16x8*)(ldsH + m*136 + ks*32 + qd*8);
    f32x4 acc4[4];
    #pragma unroll
    for (int i = 0; i < 4; ++i) { f32x4 z = {0.f,0.f,0.f,0.f}; acc4[i] = z; }
    #pragma unroll
    for (int i = 0; i < 4; ++i) {
      int cti = c*4 + i;
      const unsigned short* bp1 = W1T + (cti*16 + m)*128 + qd*8;
      #pragma unroll
      for (int ks = 0; ks < 4; ++ks)
        acc4[i] = __builtin_amdgcn_mfma_f32_16x16x32_bf16(hf[ks], *(const bf16x8*)(bp1 + ks*32), acc4[i], 0, 0, 0);
      const unsigned short* bps = WsT + (cti*16 + m)*256 + qd*8;
      #pragma unroll
      for (int ks = 0; ks < 4; ++ks)
        acc4[i] = __builtin_amdgcn_mfma_f32_16x16x32_bf16(nf[ks], *(const bf16x8*)(bps + ks*32), acc4[i], 0, 0, 0);
      #pragma unroll
      for (int ks = 0; ks < 4; ++ks)
        acc4[i] = __builtin_amdgcn_mfma_f32_16x16x32_bf16(af[ks], *(const bf16x8*)(bps + 128 + ks*32), acc4[i], 0, 0, 0);
    }
    #pragma unroll
    for (int i = 0; i < 4; ++i) {
      int col = (c*4 + i)*16 + m;
      float b1v = ldp(b1s, iblk*128 + col, f32m);
      #pragma unroll
      for (int rr = 0; rr < 4; ++rr)
        ldsF[(qd*4 + rr)*132 + col] = acc4[i][rr] + b1v;   // exact f32 staging
    }
  }
  __syncthreads();

  // ---- coalesced epilogue: resid add + RTNE pack, 32 B/lane contiguous ----
  {
    int row = tid >> 3, cg2 = tid & 7;   // 16 rows x 8 chunks of 16 cols
    int grow2 = r0 + row;
    const float* srcf = ldsF + row*132 + cg2*16;
    unsigned int outw[8];
    if (hasResid) {
      const uint4* rp = (const uint4*)(netIn + grow2*128 + cg2*16);
      uint4 ra = rp[0], rb = rp[1];
      float rs0  = lo2f(ra.x), rs1  = hi2f(ra.x), rs2  = lo2f(ra.y), rs3  = hi2f(ra.y);
      float rs4  = lo2f(ra.z), rs5  = hi2f(ra.z), rs6  = lo2f(ra.w), rs7  = hi2f(ra.w);
      float rs8  = lo2f(rb.x), rs9  = hi2f(rb.x), rs10 = lo2f(rb.y), rs11 = hi2f(rb.y);
      float rs12 = lo2f(rb.z), rs13 = hi2f(rb.z), rs14 = lo2f(rb.w), rs15 = hi2f(rb.w);
      outw[0] = (unsigned int)f2b(srcf[0]  + rs0)  | ((unsigned int)f2b(srcf[1]  + rs1)  << 16);
      outw[1] = (unsigned int)f2b(srcf[2]  + rs2)  | ((unsigned int)f2b(srcf[3]  + rs3)  << 16);
      outw[2] = (unsigned int)f2b(srcf[4]  + rs4)  | ((unsigned int)f2b(srcf[5]  + rs5)  << 16);
      outw[3] = (unsigned int)f2b(srcf[6]  + rs6)  | ((unsigned int)f2b(srcf[7]  + rs7)  << 16);
      outw[4] = (unsigned int)f2b(srcf[8]  + rs8)  | ((unsigned int)f2b(srcf[9]  + rs9)  << 16);
      outw[5] = (unsigned int)f2b(srcf[10] + rs10) | ((unsigned int)f2b(srcf[11] + rs11) << 16);
      outw[6] = (unsigned int)f2b(srcf[12] + rs12) | ((unsigned int)f2b(srcf[13] + rs13) << 16);
      outw[7] = (unsigned int)f2b(srcf[14] + rs14) | ((unsigned int)f2b(srcf[15] + rs15) << 16);
    } else {
      #pragma unroll
      for (int j = 0; j < 8; ++j)
        outw[j] = (unsigned int)f2b(srcf[2*j]) | ((unsigned int)f2b(srcf[2*j+1]) << 16);
    }
    uint4* op = (uint4*)(netOut + grow2*128 + cg2*16);
    op[0] = make_uint4(outw[0], outw[1], outw[2], outw[3]);
    op[1] = make_uint4(outw[4], outw[5], outw[6], outw[7]);
  }
}

// ---------------- final: out = net @ W_c + b_c (dtype per flag) ----------------
__global__ __launch_bounds__(256) void k_final(const unsigned short* __restrict__ netIn,
                                               const unsigned short* __restrict__ WcT,
                                               const void* __restrict__ bcv,
                                               const int* __restrict__ flagp,
                                               void* __restrict__ out){
  int tid = threadIdx.x; int w = tid >> 6, lane = tid & 63;
  int f32m = *flagp;
  int t = w >> 1, c = w & 1;
  int r0 = blockIdx.x*32 + t*16;
  int m = lane & 15, qd = lane >> 4;
  bf16x8 nf[4];
  #pragma unroll
  for (int ks = 0; ks < 4; ++ks)
    nf[ks] = *(const bf16x8*)(netIn + (r0 + m)*128 + ks*32 + qd*8);
  f32x4 acc[4];
  #pragma unroll
  for (int i = 0; i < 4; ++i) { f32x4 z = {0.f,0.f,0.f,0.f}; acc[i] = z; }
  #pragma unroll
  for (int i = 0; i < 4; ++i) {
    int cti = c*4 + i;
    const unsigned short* bp = WcT + (cti*16 + m)*128 + qd*8;
    #pragma unroll
    for (int ks = 0; ks < 4; ++ks)
      acc[i] = __builtin_amdgcn_mfma_f32_16x16x32_bf16(nf[ks], *(const bf16x8*)(bp + ks*32), acc[i], 0, 0, 0);
  }
  if (f32m) {
    float* o = (float*)out;
    #pragma unroll
    for (int i = 0; i < 4; ++i) {
      int col = (c*4 + i)*16 + m;
      float bcf = ldp(bcv, col, 1);
      #pragma unroll
      for (int rr = 0; rr < 4; ++rr)
        o[(r0 + qd*4 + rr)*128 + col] = acc[i][rr] + bcf;
    }
  } else {
    unsigned short* o = (unsigned short*)out;
    #pragma unroll
    for (int i = 0; i < 4; ++i) {
      int col = (c*4 + i)*16 + m;
      float bcf = ldp(bcv, col, 0);
      #pragma unroll
      for (int rr = 0; rr < 4; ++rr)
        o[(r0 + qd*4 + rr)*128 + col] = f2b(acc[i][rr] + bcf);
    }
  }
}

// ---------------- host launch ----------------
extern "C" void kernel_launch(void* const* d_in, const int* in_sizes, int n_in,
                              void* d_out, int out_size, void* d_ws, size_t ws_size,
                              hipStream_t stream){
  const void* p    = d_in[0];
  const void* Wpos = d_in[1];
  const void* bpos = d_in[2];
  const void* W0   = d_in[3];
  const void* b0   = d_in[4];
  const void* W1   = d_in[5];
  const void* b1   = d_in[6];
  const void* Ws   = d_in[7];
  const void* Wc_  = d_in[8];
  const void* bc_  = d_in[9];
  const void* Wo   = d_in[10];
  const void* bo   = d_in[11];
  const void* WC   = d_in[12];
  const void* bC   = d_in[13];

  char* ws = (char*)d_ws;
  int*            flag   = (int*)(ws + 0);                    //      256 B (padded)
  float4*         pf4    = (float4*)(ws + 256);               //   524288 B
  unsigned short* idx16  = (unsigned short*)(ws + 524544);    //  1310720 B
  unsigned short* wsoftb = (unsigned short*)(ws + 1835264);   //  7864320 B
  unsigned short* netA   = (unsigned short*)(ws + 9699584);   //  8388608 B
  unsigned short* wT     = (unsigned short*)(ws + 18088192);  //  1212416 B (total ~19.3 MB)

  k_detect     <<<dim3(1),     dim3(64),  0, stream>>>((const unsigned short*)Wpos, flag);
  k_prep_points<<<dim3(128),   dim3(256), 0, stream>>>(p, flag, pf4);
  k_net0       <<<dim3(16384), dim3(256), 0, stream>>>(pf4, Wpos, bpos, flag, netA);
  k_transpose  <<<dim3(2368),  dim3(256), 0, stream>>>(W0, W1, Ws, Wo, WC, flag, wT);
  k_knn        <<<dim3(512),   dim3(256), 0, stream>>>(pf4, Wc_, bc_, flag, idx16, wsoftb);

  unsigned short* a   = netA;
  unsigned short* bpt = (unsigned short*)d_out;   // d_out as bf16 ping-pong scratch
  for (int i = 0; i < 6; ++i) {
    k_block<<<dim3(2048), dim3(128), 0, stream>>>(a, bpt, idx16, wsoftb, wT,
                                                  b0, b1, bo, flag, i, (i > 0) ? 1 : 0);
    unsigned short* t = a; a = bpt; bpt = t;
  }
  // 6 swaps: final net is in netA (== a)
  k_final<<<dim3(1024), dim3(256), 0, stream>>>(a, wT + 589824, bC, flag, d_out);
}